// Round 1
// baseline (61.780 us; speedup 1.0000x reference)
//
#include <hip/hip_runtime.h>

#define BATCH 8
#define DIM   128
#define TH    16            // output h-rows per block
#define TD    8             // d-planes per block
#define ROWS  (TH + 2)      // 18 staged rows (with h halo)
#define COLS  132           // 128 + 2 halo, padded to multiple of 4 for 16B alignment
#define PLANE_ELEMS (ROWS * COLS)

__global__ __launch_bounds__(256) void conv3d_circ_kernel(
    const float* __restrict__ x, const float* __restrict__ kern,
    float* __restrict__ out)
{
    __shared__ __align__(16) float lds[3][ROWS][COLS];

    const int tid = threadIdx.x;
    const int bid = blockIdx.x;
    const int b   = bid >> 7;          // 8 batches
    const int ht  = (bid >> 4) & 7;    // 8 h-tiles of 16
    const int dt  = bid & 15;          // 16 d-chunks of 8
    const int h0  = ht * TH;
    const int d0  = dt * TD;

    // 27 kernel weights -> registers (uniform address -> scalar loads)
    float K[27];
#pragma unroll
    for (int i = 0; i < 27; ++i) K[i] = kern[i];

    const float* xb = x   + (size_t)b * DIM * DIM * DIM;
    float*       ob = out + (size_t)b * DIM * DIM * DIM;

    // Stage plane (logical index l, wrapped) into ring slot (l mod 3).
    auto load_plane = [&](int l) {
        const int slot = (int)((unsigned)(l + 3) % 3u);
        const int pd   = l & (DIM - 1);
        const float* xp = xb + pd * DIM * DIM;
        for (int e = tid; e < PLANE_ELEMS; e += 256) {
            const int r = e / COLS;
            const int c = e - r * COLS;
            const int hg = (h0 - 1 + r) & (DIM - 1);
            const int w  = (c - 1) & (DIM - 1);   // col 0 = x[127], col 129 = x[0]
            lds[slot][r][c] = xp[hg * DIM + w];
        }
    };

    load_plane(d0 - 1);
    load_plane(d0);

    const int wq  = (tid & 31) * 4;   // 4 outputs along w per thread
    const int hr0 = tid >> 5;         // 8 h-rows covered per pass, 2 passes

    for (int i = 0; i < TD; ++i) {
        const int d = d0 + i;
        load_plane(d + 1);            // overwrites slot of plane d-2 (done last iter)
        __syncthreads();

        const int s0 = (int)((unsigned)(d + 2) % 3u);  // plane d-1
        const int s1 = (int)((unsigned)(d + 3) % 3u);  // plane d
        const int s2 = (int)((unsigned)(d + 4) % 3u);  // plane d+1
        const int sl[3] = {s0, s1, s2};

#pragma unroll
        for (int hh_i = 0; hh_i < 2; ++hh_i) {
            const int hh = hr0 + hh_i * 8;             // output row within tile
            float4 acc = make_float4(0.f, 0.f, 0.f, 0.f);
#pragma unroll
            for (int cd = 0; cd < 3; ++cd) {
                const float* pl = &lds[sl[cd]][0][0];
#pragma unroll
                for (int ch = 0; ch < 3; ++ch) {
                    const float* rowp = pl + (hh + ch) * COLS + wq;
                    const float4 a  = *(const float4*)(rowp);        // cols wq..wq+3
                    const float2 bb = *(const float2*)(rowp + 4);    // cols wq+4..wq+5
                    const float k0 = K[(cd * 3 + ch) * 3 + 0];
                    const float k1 = K[(cd * 3 + ch) * 3 + 1];
                    const float k2 = K[(cd * 3 + ch) * 3 + 2];
                    acc.x += k0 * a.x + k1 * a.y + k2 * a.z;
                    acc.y += k0 * a.y + k1 * a.z + k2 * a.w;
                    acc.z += k0 * a.z + k1 * a.w + k2 * bb.x;
                    acc.w += k0 * a.w + k1 * bb.x + k2 * bb.y;
                }
            }
            *(float4*)&ob[(d * DIM + (h0 + hh)) * DIM + wq] = acc;
        }
        __syncthreads();
    }
}

extern "C" void kernel_launch(void* const* d_in, const int* in_sizes, int n_in,
                              void* d_out, int out_size, void* d_ws, size_t ws_size,
                              hipStream_t stream) {
    const float* x    = (const float*)d_in[0];
    const float* kern = (const float*)d_in[1];
    float*       out  = (float*)d_out;
    // grid: 8 batches x 8 h-tiles x 16 d-chunks = 1024 blocks
    conv3d_circ_kernel<<<dim3(1024), dim3(256), 0, stream>>>(x, kern, out);
}